// Round 4
// baseline (129.110 us; speedup 1.0000x reference)
//
#include <hip/hip_runtime.h>
#include <hip/hip_cooperative_groups.h>
#include <math.h>

namespace cg = cooperative_groups;

#define G 1200
#define NIN 10
#define NHE 300
#define NINC 4800
#define ALPHA 0.005f
#define BETA 5e-5f
#define BN_EPS 1e-5f
#define NBLK 256
#define NTHR 1024

struct Params {
    const float *x, *edge1, *edge2, *W1, *b1, *infer_w, *infer_b;
    const float *e1w, *e1b, *e2w, *e2b;
    const float *n1w, *n1b, *n2w, *n2b;
    const float *m1w, *m1b, *m2w, *m2b, *m3w, *m3b;
    const float *hgw, *hgb;
    const int *hn, *he;
    float4 *xfeat2, *upd2;
    float *efeat;
    int *eh;
    float4 *out;
};

// 4*G float4 (76800B) + 4*G float (19200B) + small cross-wave buffers ~= 96.7 KB.
// <= 160 KB/CU -> exactly 1 block/CU at 1024 threads.
struct Smem {
    float4 h4[4 * G];     // per (batch,node): feature vec (round input)
    float  aarr[4 * G];   // per (batch,node): source-side gate term a_j
    float  t[4][4][5];    // [slot][batch][recv0..3, sum_s]
    float  hvs[4][4][4];  // [slot][batch][feat]
    float  stats[4][2];   // [slot][mean, rstd]
    float  bsf[4][4];     // [slot][feat]
};

__device__ __forceinline__ float eluf(float x) { return x > 0.f ? x : __expf(x) - 1.f; }
__device__ __forceinline__ float sigf(float x) { return 1.f / (1.f + __expf(-x)); }
__device__ __forceinline__ float wred(float v) {
#pragma unroll
    for (int o = 32; o > 0; o >>= 1) v += __shfl_down(v, o, 64);
    return v;
}

// Edge round over staged LDS operands. slot = tid>>8 handles gene i; wave (tid>>6)&3 = batch.
// MODE 1: round1 -> elu(z*W1diag+b1) -> BN -> write xfeat2.
// MODE 2: round2 -> BN -> write upd2; scatter sum_b hgw@upd2[b,i] into efeat/eh.
template <int MODE>
__device__ void round_phase(const Params& p, Smem& sm, int blk, int tid,
                            const float* __restrict__ edge, float coef,
                            const float* __restrict__ ew, const float* __restrict__ eb,
                            const float* __restrict__ nw, const float* __restrict__ nb,
                            const float* __restrict__ mw, const float* __restrict__ mb) {
    const int lane = tid & 63;
    const int b = (tid >> 6) & 3;
    const int slot = tid >> 8;
    const int tslot = tid & 255;

    for (int s = 0; s < 2; ++s) {
        const int i = (s << 10) + (blk << 2) + slot;
        const bool active = (i < G);

        if (active) {
            const float* erow = edge + (size_t)i * G;
            float4 hi = sm.h4[b * G + i];
            float cb = ew[4] * hi.x + ew[5] * hi.y + ew[6] * hi.z + ew[7] * hi.w + eb[0];
            float a0 = 0.f, a1 = 0.f, a2 = 0.f, a3 = 0.f, a4 = 0.f;
            for (int j = lane; j < G; j += 64) {
                float m = erow[j];
                float mask = (m == 0.f) ? coef : m;  // edge + coef*(edge==0)
                float4 hj = sm.h4[b * G + j];
                float sg = sigf(sm.aarr[b * G + j] + cb) * mask;
                a0 += sg * hj.x;
                a1 += sg * hj.y;
                a2 += sg * hj.z;
                a3 += sg * hj.w;
                a4 += sg;
            }
            a0 = wred(a0); a1 = wred(a1); a2 = wred(a2); a3 = wred(a3); a4 = wred(a4);
            if (lane == 0) {
                sm.t[slot][b][0] = a0; sm.t[slot][b][1] = a1; sm.t[slot][b][2] = a2;
                sm.t[slot][b][3] = a3; sm.t[slot][b][4] = a4;
            }
        }
        __syncthreads();

        if (active && lane == 0) {
            float4 xi4 = sm.h4[b * G + i];
            float xi[4] = {xi4.x, xi4.y, xi4.z, xi4.w};
            float ssum = sm.t[slot][b][4];
            float r8[8];
#pragma unroll
            for (int k = 0; k < 4; ++k) { r8[k] = sm.t[slot][b][k]; r8[4 + k] = xi[k] * ssum; }
            float r[4];
#pragma unroll
            for (int f = 0; f < 4; ++f) {
                float sv = nb[f];
#pragma unroll
                for (int k = 0; k < 8; ++k) sv += nw[f * 8 + k] * r8[k];
                r[f] = eluf(sv);
            }
            float w1d = 0.f, b1i = 0.f;
            if (MODE == 1) { w1d = p.W1[(size_t)i * G + i]; b1i = p.b1[i]; }
#pragma unroll
            for (int f = 0; f < 4; ++f) {
                float sv = mb[f];
#pragma unroll
                for (int k = 0; k < 4; ++k) sv += mw[f * 8 + k] * r[k] + mw[f * 8 + 4 + k] * xi[k];
                float z = eluf(sv);
                sm.hvs[slot][b][f] = (MODE == 1) ? eluf(z * w1d + b1i) : z;
            }
        }
        __syncthreads();

        if (tslot == 0) {  // BN stats per gene over 16 values (garbage if slot inactive: unused)
            float mean = 0.f;
#pragma unroll
            for (int bb = 0; bb < 4; ++bb)
#pragma unroll
                for (int f = 0; f < 4; ++f) mean += sm.hvs[slot][bb][f];
            mean *= (1.f / 16.f);
            float var = 0.f;
#pragma unroll
            for (int bb = 0; bb < 4; ++bb)
#pragma unroll
                for (int f = 0; f < 4; ++f) { float d = sm.hvs[slot][bb][f] - mean; var += d * d; }
            var *= (1.f / 16.f);
            sm.stats[slot][0] = mean;
            sm.stats[slot][1] = rsqrtf(var + BN_EPS);
        }
        __syncthreads();

        if (active && lane == 0) {
            const float mean = sm.stats[slot][0], sc = sm.stats[slot][1];
            float hv[4];
#pragma unroll
            for (int f = 0; f < 4; ++f) hv[f] = (sm.hvs[slot][b][f] - mean) * sc;
            if (MODE == 1) {
                p.xfeat2[b * G + i] = make_float4(hv[0], hv[1], hv[2], hv[3]);
            } else {
                p.upd2[b * G + i] = make_float4(hv[0], hv[1], hv[2], hv[3]);
                sm.hvs[slot][b][0] = hv[0]; sm.hvs[slot][b][1] = hv[1];
                sm.hvs[slot][b][2] = hv[2]; sm.hvs[slot][b][3] = hv[3];
            }
        }

        if (MODE == 2) {
            __syncthreads();
            if (active && tslot < 4) {
                const int f = tslot;
                float sv = 0.f;
#pragma unroll
                for (int bb = 0; bb < 4; ++bb)
#pragma unroll
                    for (int k = 0; k < 4; ++k) sv += p.hgw[f * 4 + k] * sm.hvs[slot][bb][k];
                sm.bsf[slot][f] = sv;
            }
            __syncthreads();
            if (active) {
                const float v0 = sm.bsf[slot][0], v1 = sm.bsf[slot][1];
                const float v2 = sm.bsf[slot][2], v3 = sm.bsf[slot][3];
                for (int cI = tslot; cI < NINC; cI += 256) {
                    if (p.hn[cI] == i) {
                        int e = p.he[cI];
                        atomicAdd(&p.eh[e], 1);
                        atomicAdd(&p.efeat[e * 4 + 0], v0);
                        atomicAdd(&p.efeat[e * 4 + 1], v1);
                        atomicAdd(&p.efeat[e * 4 + 2], v2);
                        atomicAdd(&p.efeat[e * 4 + 3], v3);
                    }
                }
            }
        }
        __syncthreads();  // protect t/hvs/stats reuse across sweeps
    }
}

// Phase 1: block 0 zeros efeat/eh; every block computes infer for all 4800 nodes into LDS; round1.
__device__ void phase1(const Params& p, Smem& sm, int blk, int tid) {
    if (blk == 0) {
        for (int q = tid; q < NHE * 4; q += NTHR) p.efeat[q] = 0.f;
        for (int q = tid; q < NHE; q += NTHR) p.eh[q] = 0;
    }
    for (int n = tid; n < 4 * G; n += NTHR) {
        const float* xp = p.x + n * NIN;
        float h[4];
#pragma unroll
        for (int f = 0; f < 4; ++f) {
            float sv = p.infer_b[f];
#pragma unroll
            for (int k = 0; k < NIN; ++k) sv += p.infer_w[f * NIN + k] * xp[k];
            h[f] = eluf(sv);
        }
        sm.h4[n] = make_float4(h[0], h[1], h[2], h[3]);
        sm.aarr[n] = p.e1w[0] * h[0] + p.e1w[1] * h[1] + p.e1w[2] * h[2] + p.e1w[3] * h[3];
    }
    __syncthreads();
    round_phase<1>(p, sm, blk, tid, p.edge1, ALPHA, p.e1w, p.e1b, p.n1w, p.n1b, p.m1w, p.m1b);
}

// Phase 2: stage xfeat2 from global into LDS; round2 + scatter.
__device__ void phase2(const Params& p, Smem& sm, int blk, int tid) {
    for (int n = tid; n < 4 * G; n += NTHR) {
        float4 v = p.xfeat2[n];
        sm.h4[n] = v;
        sm.aarr[n] = p.e2w[0] * v.x + p.e2w[1] * v.y + p.e2w[2] * v.z + p.e2w[3] * v.w;
    }
    __syncthreads();
    round_phase<2>(p, sm, blk, tid, p.edge2, BETA, p.e2w, p.e2b, p.n2w, p.n2b, p.m2w, p.m2b);
}

// Phase 3: hypergraph gather (batch-degenerate) + final MLP.
__device__ void phase3(const Params& p, Smem& sm, int blk, int tid) {
    const int lane = tid & 63;
    const int b = (tid >> 6) & 3;
    const int slot = tid >> 8;
    const int tslot = tid & 255;

    for (int s = 0; s < 2; ++s) {
        const int i = (s << 10) + (blk << 2) + slot;
        const bool active = (i < G);
        float a0 = 0.f, a1 = 0.f, a2 = 0.f, a3 = 0.f, cf = 0.f;
        if (active) {
            for (int cI = tslot; cI < NINC; cI += 256) {
                if (p.hn[cI] == i) {
                    int e = p.he[cI];
                    float binv = 0.25f / (float)p.eh[e];  // bdeg = BSZ * hist(edges)
                    a0 += p.efeat[e * 4 + 0] * binv;
                    a1 += p.efeat[e * 4 + 1] * binv;
                    a2 += p.efeat[e * 4 + 2] * binv;
                    a3 += p.efeat[e * 4 + 3] * binv;
                    cf += 1.f;
                }
            }
        }
        a0 = wred(a0); a1 = wred(a1); a2 = wred(a2); a3 = wred(a3); cf = wred(cf);
        if (lane == 0) {
            sm.t[slot][b][0] = a0; sm.t[slot][b][1] = a1; sm.t[slot][b][2] = a2;
            sm.t[slot][b][3] = a3; sm.t[slot][b][4] = cf;
        }
        __syncthreads();

        if (active && lane == 0) {
            float dg = sm.t[slot][0][4] + sm.t[slot][1][4] + sm.t[slot][2][4] + sm.t[slot][3][4];
            float dinv = dg > 0.f ? 1.f / dg : 0.f;
            float hxp[4];
#pragma unroll
            for (int f = 0; f < 4; ++f) {
                float hx = (sm.t[slot][0][f] + sm.t[slot][1][f] + sm.t[slot][2][f] +
                            sm.t[slot][3][f]) * dinv;
                hxp[f] = eluf(hx + p.hgb[f]);
            }
            float4 u4 = p.upd2[b * G + i];
            float u[4] = {u4.x, u4.y, u4.z, u4.w};
            float o4[4];
#pragma unroll
            for (int f = 0; f < 4; ++f) {
                float sv = p.m3b[f];
#pragma unroll
                for (int k = 0; k < 4; ++k)
                    sv += p.m3w[f * 8 + k] * u[k] + p.m3w[f * 8 + 4 + k] * hxp[k];
                o4[f] = eluf(sv);
            }
            p.out[b * G + i] = make_float4(o4[0], o4[1], o4[2], o4[3]);
        }
        __syncthreads();
    }
}

// Fused cooperative kernel: 256 blocks (1/CU guaranteed: 96KB LDS, VGPR<=128 via bounds).
__global__ __launch_bounds__(NTHR)
void fused_kernel(Params p) {
    __shared__ Smem sm;
    cg::grid_group grid = cg::this_grid();
    phase1(p, sm, blockIdx.x, threadIdx.x);
    grid.sync();
    phase2(p, sm, blockIdx.x, threadIdx.x);
    grid.sync();
    phase3(p, sm, blockIdx.x, threadIdx.x);
}

// Fallback: same bodies as 3 plain kernels.
__global__ __launch_bounds__(NTHR) void k_p1(Params p) { __shared__ Smem sm; phase1(p, sm, blockIdx.x, threadIdx.x); }
__global__ __launch_bounds__(NTHR) void k_p2(Params p) { __shared__ Smem sm; phase2(p, sm, blockIdx.x, threadIdx.x); }
__global__ __launch_bounds__(NTHR) void k_p3(Params p) { __shared__ Smem sm; phase3(p, sm, blockIdx.x, threadIdx.x); }

extern "C" void kernel_launch(void* const* d_in, const int* in_sizes, int n_in,
                              void* d_out, int out_size, void* d_ws, size_t ws_size,
                              hipStream_t stream) {
    Params p;
    p.x       = (const float*)d_in[0];
    p.edge1   = (const float*)d_in[1];
    p.edge2   = (const float*)d_in[2];
    p.W1      = (const float*)d_in[3];
    p.b1      = (const float*)d_in[4];
    p.infer_w = (const float*)d_in[5];
    p.infer_b = (const float*)d_in[6];
    p.e1w     = (const float*)d_in[7];
    p.e1b     = (const float*)d_in[8];
    p.e2w     = (const float*)d_in[9];
    p.e2b     = (const float*)d_in[10];
    p.n1w     = (const float*)d_in[11];
    p.n1b     = (const float*)d_in[12];
    p.n2w     = (const float*)d_in[13];
    p.n2b     = (const float*)d_in[14];
    p.m1w     = (const float*)d_in[15];
    p.m1b     = (const float*)d_in[16];
    p.m2w     = (const float*)d_in[17];
    p.m2b     = (const float*)d_in[18];
    p.m3w     = (const float*)d_in[19];
    p.m3b     = (const float*)d_in[20];
    p.hgw     = (const float*)d_in[21];
    p.hgb     = (const float*)d_in[22];
    p.hn      = (const int*)d_in[23];
    p.he      = (const int*)d_in[24];

    char* ws = (char*)d_ws;
    p.xfeat2 = (float4*)(ws + 0);       // 4800*16 = 76800
    p.upd2   = (float4*)(ws + 76800);   // 76800
    p.efeat  = (float*)(ws + 153600);   // 1200 f32 = 4800
    p.eh     = (int*)(ws + 158400);     // 300 i32 = 1200
    p.out    = (float4*)d_out;

    void* args[] = {(void*)&p};
    hipError_t err = hipLaunchCooperativeKernel((const void*)fused_kernel,
                                                dim3(NBLK), dim3(NTHR), args, 0, stream);
    if (err != hipSuccess) {
        k_p1<<<NBLK, NTHR, 0, stream>>>(p);
        k_p2<<<NBLK, NTHR, 0, stream>>>(p);
        k_p3<<<NBLK, NTHR, 0, stream>>>(p);
    }
}